// Round 9
// baseline (144.488 us; speedup 1.0000x reference)
//
#include <hip/hip_runtime.h>
#include <hip/hip_bf16.h>

namespace {
constexpr int kB    = 8192;
constexpr int kNB   = 64;
constexpr int kF    = 256;
constexpr int kK    = 8;
constexpr int kKS   = 5;
constexpr int kH    = 256;
constexpr int kOUT  = 128;
constexpr int kXR   = 9;   // x rows (1 node + 8 topk)
constexpr int kTO   = 5;   // conv1 output positions
constexpr int kBM   = 32;  // batch rows per block (1 block/CU, halves L2 weight traffic)

constexpr int XPAD = 258;   // A-row stride 9*258 el = 1161 dw ≡ 9 (odd) mod 32 -> conflict-free
constexpr int HPAD = 1290;  // h row stride 645 dw ≡ 5 (odd) mod 32 -> conflict-free

constexpr int DEPTH = 12;   // gather pipeline depth (48 VGPR)

// workspace layout (bytes)
constexpr size_t W1T_OFF = 0;                                   // bf16 [5][256(hc)][256(f)]
constexpr size_t W2T_OFF = W1T_OFF + (size_t)kKS * kH * kF * 2; // bf16 [128(o)][1280(k)]

typedef __attribute__((ext_vector_type(8))) short short8; // 8 bf16 (A/B frag)
typedef __attribute__((ext_vector_type(4))) float f32x4;  // C/D frag / gather vector
}

using bf16 = __hip_bfloat16;

__device__ __forceinline__ unsigned short f2bf(float f) {
  bf16 h = __float2bfloat16(f);
  return *reinterpret_cast<unsigned short*>(&h);
}

// ---------------- kernel 1: weight convert/transpose to bf16 ----------------
__global__ void convert_weights(const float* __restrict__ W1,
                                const float* __restrict__ W2,
                                bf16* __restrict__ w1t, bf16* __restrict__ w2t)
{
  const int i = blockIdx.x * 256 + threadIdx.x;
  const int stride = gridDim.x * 256;
  // W1T[dt][hc][f] = W1[dt][f][hc]
  for (int idx = i; idx < kKS * kH * kF; idx += stride) {
    const int f  = idx & 255;
    const int hc = (idx >> 8) & 255;
    const int dt = idx >> 16;
    w1t[idx] = __float2bfloat16(W1[(dt * kF + f) * kH + hc]);
  }
  // W2T[o][dt*256+hc] = W2[dt][hc][o]
  for (int idx = i; idx < kOUT * kKS * kH; idx += stride) {
    const int k = idx % (kKS * kH);
    const int o = idx / (kKS * kH);
    w2t[idx] = __float2bfloat16(W2[k * kOUT + o]);
  }
}

// ---------------- kernel 2: fused gather+topk+conv1+conv2 ----------------
// kBM=32, 512 threads (8 waves), grid=256 -> 1 block/CU. Each wave gathers
// 4 batch rows (12-deep rolling pipeline), then owns a 32-wide hc strip
// over TWO 16-row m-tiles in GEMM1 (weights amortized 2x vs kBM=16) and a
// 16-wide o strip over two m-tiles in GEMM2.
__global__ __launch_bounds__(512, 2)
void fused_all(const int* __restrict__ node_ids,
               const int* __restrict__ neighbors,
               const float* __restrict__ feat,
               const bf16* __restrict__ w1t, const bf16* __restrict__ w2t,
               const float* __restrict__ b1, const float* __restrict__ b2,
               float* __restrict__ out)
{
  __shared__ bf16 smem[kBM * kXR * XPAD];  // 148608 B -> 1 block/CU
  bf16* xs = smem;
  bf16* hs = smem;   // h reuses x region after barrier (32*1290*2 = 82560 B)

  const int tid  = threadIdx.x;
  const int wave = tid >> 6;       // 0..7
  const int lane = tid & 63;
  const int r = lane & 15;
  const int q = lane >> 4;
  const int bbase = blockIdx.x * kBM;
  const int f4 = lane << 2;

  // ================= gather + per-channel top-8 -> LDS (bf16) =================
  int   myn4[4];
  f32x4 node4[4];
#pragma unroll
  for (int bb = 0; bb < 4; ++bb) {
    const int b = bbase + wave * 4 + bb;
    myn4[bb]  = neighbors[(size_t)b * kNB + lane];
    node4[bb] = *reinterpret_cast<const f32x4*>(feat + (size_t)node_ids[b] * kF + f4);
  }

#pragma unroll
  for (int bb = 0; bb < 4; ++bb) {
    const int bl  = wave * 4 + bb;                 // local batch row 0..31
    const int myn = myn4[bb];

    float tk[4][kK];
#pragma unroll
    for (int c = 0; c < 4; ++c)
#pragma unroll
      for (int k = 0; k < kK; ++k) tk[c][k] = -INFINITY;

    // sorted insert via med3 network: 8 ops/channel, 1-deep chain.
    auto ins4 = [&](const f32x4& v) {
#pragma unroll
      for (int c = 0; c < 4; ++c) {
        const float vc = v[c];
        float nt[kK];
        nt[0] = fmaxf(tk[c][0], vc);
#pragma unroll
        for (int k = 1; k < kK; ++k)
          nt[k] = __builtin_amdgcn_fmed3f(tk[c][k - 1], tk[c][k], vc);
#pragma unroll
        for (int k = 0; k < kK; ++k) tk[c][k] = nt[k];
      }
    };

    f32x4 buf[DEPTH];
#pragma unroll
    for (int i = 0; i < DEPTH; ++i) {
      const int rr = __builtin_amdgcn_readlane(myn, i);
      buf[i] = *reinterpret_cast<const f32x4*>(feat + (size_t)rr * kF + f4);
    }
#pragma unroll
    for (int n = 0; n < kNB - DEPTH; ++n) {        // 52 steady iterations
      const f32x4 v = buf[n % DEPTH];
      const int rr = __builtin_amdgcn_readlane(myn, n + DEPTH);
      buf[n % DEPTH] = *reinterpret_cast<const f32x4*>(feat + (size_t)rr * kF + f4);
      ins4(v);
    }
#pragma unroll
    for (int n = kNB - DEPTH; n < kNB; ++n) ins4(buf[n % DEPTH]);

    bf16* xb = xs + (size_t)bl * kXR * XPAD + f4;
    {
      ushort4 s = {f2bf(node4[bb][0]), f2bf(node4[bb][1]),
                   f2bf(node4[bb][2]), f2bf(node4[bb][3])};
      *reinterpret_cast<ushort4*>(xb) = s;
    }
#pragma unroll
    for (int k = 0; k < kK; ++k) {
      ushort4 s = {f2bf(tk[0][k]), f2bf(tk[1][k]), f2bf(tk[2][k]), f2bf(tk[3][k])};
      *reinterpret_cast<ushort4*>(xb + (size_t)(1 + k) * XPAD) = s;
    }
  }
  __syncthreads();

  // ===== GEMM1: h[b][t][hc] = sum_dt,f x[b][t+dt][f]*W1[dt][f][hc] + b1 =====
  // wave owns hc strip [wave*32, wave*32+32), over 2 m-tiles of 16 rows.
  const int ntb = wave * 32;
  f32x4 acc[2][kTO][2];
#pragma unroll
  for (int n = 0; n < 2; ++n) {
    const float bv = b1[ntb + n * 16 + r];
#pragma unroll
    for (int mt = 0; mt < 2; ++mt)
#pragma unroll
      for (int m = 0; m < kTO; ++m) acc[mt][m][n] = (f32x4){bv, bv, bv, bv};
  }

  for (int kk = 0; kk < 8; ++kk) {
    short8 a[2][kXR];
#pragma unroll
    for (int mt = 0; mt < 2; ++mt)
#pragma unroll
      for (int rr = 0; rr < kXR; ++rr)
        a[mt][rr] = *reinterpret_cast<const short8*>(
            &xs[((mt * 16 + r) * kXR + rr) * XPAD + kk * 32 + q * 8]);
#pragma unroll
    for (int dt = 0; dt < kKS; ++dt) {
      short8 bfr[2];
#pragma unroll
      for (int n = 0; n < 2; ++n)
        bfr[n] = *reinterpret_cast<const short8*>(
            &w1t[((size_t)(dt * kH + ntb + n * 16 + r)) * kF + kk * 32 + q * 8]);
#pragma unroll
      for (int mt = 0; mt < 2; ++mt)
#pragma unroll
        for (int m = 0; m < kTO; ++m)
#pragma unroll
          for (int n = 0; n < 2; ++n)
            acc[mt][m][n] = __builtin_amdgcn_mfma_f32_16x16x32_bf16(
                a[mt][m + dt], bfr[n], acc[mt][m][n], 0, 0, 0);
    }
  }
  __syncthreads();  // all waves done reading xs; safe to overwrite with h

  // ---- write h (bf16) into LDS: hs[row][t*256 + hc]  (C/D: col=lane&15, row=q*4+j) ----
#pragma unroll
  for (int mt = 0; mt < 2; ++mt)
#pragma unroll
    for (int m = 0; m < kTO; ++m)
#pragma unroll
      for (int n = 0; n < 2; ++n)
#pragma unroll
        for (int j = 0; j < 4; ++j)
          hs[(mt * 16 + q * 4 + j) * HPAD + m * kH + ntb + n * 16 + r] =
              __float2bfloat16(acc[mt][m][n][j]);
  __syncthreads();

  // ===== GEMM2: out[b][o] = sum_k h[b][k]*W2T[o][k] + b2 =====
  // wave owns o strip [wave*16, wave*16+16), over 2 m-tiles of 16 rows.
  const int ob = wave * 16;
  f32x4 acc2[2];
  {
    const float bv = b2[ob + r];
#pragma unroll
    for (int mt = 0; mt < 2; ++mt) acc2[mt] = (f32x4){bv, bv, bv, bv};
  }
  for (int ks = 0; ks < 40; ++ks) {
    short8 b2f = *reinterpret_cast<const short8*>(
        &w2t[(size_t)(ob + r) * (kKS * kH) + ks * 32 + q * 8]);
#pragma unroll
    for (int mt = 0; mt < 2; ++mt) {
      short8 a2 = *reinterpret_cast<const short8*>(
          &hs[(mt * 16 + r) * HPAD + ks * 32 + q * 8]);
      acc2[mt] = __builtin_amdgcn_mfma_f32_16x16x32_bf16(a2, b2f, acc2[mt], 0, 0, 0);
    }
  }
#pragma unroll
  for (int mt = 0; mt < 2; ++mt)
#pragma unroll
    for (int j = 0; j < 4; ++j)
      out[(size_t)(bbase + mt * 16 + q * 4 + j) * kOUT + ob + r] = acc2[mt][j];
}

extern "C" void kernel_launch(void* const* d_in, const int* in_sizes, int n_in,
                              void* d_out, int out_size, void* d_ws, size_t ws_size,
                              hipStream_t stream) {
  const int*   node_ids  = (const int*)  d_in[0];
  const int*   neighbors = (const int*)  d_in[1];
  const float* feat      = (const float*)d_in[2];
  const float* W1        = (const float*)d_in[3];
  const float* b1        = (const float*)d_in[4];
  const float* W2        = (const float*)d_in[5];
  const float* b2        = (const float*)d_in[6];
  float* out = (float*)d_out;

  char* ws = (char*)d_ws;
  bf16* w1t = (bf16*)(ws + W1T_OFF);
  bf16* w2t = (bf16*)(ws + W2T_OFF);

  convert_weights<<<1024, 256, 0, stream>>>(W1, W2, w1t, w2t);
  fused_all<<<kB / kBM, 512, 0, stream>>>(node_ids, neighbors, feat, w1t, w2t, b1, b2, out);
}

// Round 10
// 144.042 us; speedup vs baseline: 1.0031x; 1.0031x over previous
//
#include <hip/hip_runtime.h>
#include <hip/hip_bf16.h>

namespace {
constexpr int kB    = 8192;
constexpr int kNB   = 64;
constexpr int kF    = 256;
constexpr int kK    = 8;
constexpr int kKS   = 5;
constexpr int kH    = 256;
constexpr int kOUT  = 128;
constexpr int kXR   = 9;   // x rows (1 node + 8 topk)
constexpr int kTO   = 5;   // conv1 output positions
constexpr int kBM   = 16;  // batch rows per tile
constexpr int kTiles = 2;  // tiles per persistent block

constexpr int XPAD = 258;   // A-row stride 9*258 el = 1161 dw ≡ 9 (odd) mod 32 -> conflict-free
constexpr int HPAD = 1290;  // h row stride 645 dw ≡ 5 (odd) mod 32 -> conflict-free

// workspace layout (bytes)
constexpr size_t W1T_OFF = 0;                                   // bf16 [5][256(hc)][256(f)]
constexpr size_t W2T_OFF = W1T_OFF + (size_t)kKS * kH * kF * 2; // bf16 [128(o)][1280(k)]

typedef __attribute__((ext_vector_type(8))) short short8; // 8 bf16 (A/B frag)
typedef __attribute__((ext_vector_type(4))) float f32x4;  // C/D frag / gather vector
}

using bf16 = __hip_bfloat16;

__device__ __forceinline__ unsigned short f2bf(float f) {
  bf16 h = __float2bfloat16(f);
  return *reinterpret_cast<unsigned short*>(&h);
}

// sorted-insert of 4 independent channels via med3 network (8 ops, 1-deep chain)
__device__ __forceinline__ void ins4(const f32x4& v, float (&tk)[4][kK]) {
#pragma unroll
  for (int c = 0; c < 4; ++c) {
    const float vc = v[c];
    float nt[kK];
    nt[0] = fmaxf(tk[c][0], vc);
#pragma unroll
    for (int k = 1; k < kK; ++k)
      nt[k] = __builtin_amdgcn_fmed3f(tk[c][k - 1], tk[c][k], vc);
#pragma unroll
    for (int k = 0; k < kK; ++k) tk[c][k] = nt[k];
  }
}

__device__ __forceinline__ f32x4 rowload(const float* feat, int myn, int idx, int f4) {
  const unsigned rr = (unsigned)__builtin_amdgcn_readlane(myn, idx);
  return *reinterpret_cast<const f32x4*>(feat + (size_t)rr * kF + f4);
}

__device__ __forceinline__ void store_x(bf16* xb, const f32x4& nodev, float (&tk)[4][kK]) {
  ushort4 s0 = {f2bf(nodev[0]), f2bf(nodev[1]), f2bf(nodev[2]), f2bf(nodev[3])};
  *reinterpret_cast<ushort4*>(xb) = s0;
#pragma unroll
  for (int k = 0; k < kK; ++k) {
    ushort4 s = {f2bf(tk[0][k]), f2bf(tk[1][k]), f2bf(tk[2][k]), f2bf(tk[3][k])};
    *reinterpret_cast<ushort4*>(xb + (size_t)(1 + k) * XPAD) = s;
  }
}

// plain (unwoven) gather of one batch row: 8-deep rolling pipeline, static idx
__device__ __forceinline__ void gather_row(const float* feat, int myn, int f4,
                                           const f32x4& nodev, bf16* xb) {
  float tk[4][kK];
#pragma unroll
  for (int c = 0; c < 4; ++c)
#pragma unroll
    for (int k = 0; k < kK; ++k) tk[c][k] = -INFINITY;
  f32x4 buf[8];
#pragma unroll
  for (int i = 0; i < 8; ++i) buf[i] = rowload(feat, myn, i, f4);
#pragma unroll
  for (int g = 0; g < 8; ++g)
#pragma unroll
    for (int i = 0; i < 8; ++i) {
      const f32x4 v = buf[i];
      if (g < 7) buf[i] = rowload(feat, myn, g * 8 + i + 8, f4);
      ins4(v, tk);
    }
  store_x(xb, nodev, tk);
}

// ---------------- kernel 1: weight convert/transpose to bf16 ----------------
__global__ void convert_weights(const float* __restrict__ W1,
                                const float* __restrict__ W2,
                                bf16* __restrict__ w1t, bf16* __restrict__ w2t)
{
  const int i = blockIdx.x * 256 + threadIdx.x;
  const int stride = gridDim.x * 256;
  for (int idx = i; idx < kKS * kH * kF; idx += stride) {
    const int f  = idx & 255;
    const int hc = (idx >> 8) & 255;
    const int dt = idx >> 16;
    w1t[idx] = __float2bfloat16(W1[(dt * kF + f) * kH + hc]);
  }
  for (int idx = i; idx < kOUT * kKS * kH; idx += stride) {
    const int k = idx % (kKS * kH);
    const int o = idx / (kKS * kH);
    w2t[idx] = __float2bfloat16(W2[k * kOUT + o]);
  }
}

// ---------------- kernel 2: persistent fused pipeline ----------------
// grid=256 (1 block/CU), 512 threads (8 waves). Each block owns tiles
// {bid, bid+256}. Gather(t1) is woven into conv(t0): GEMM1's kk-loop
// carries 8 rolling-pipeline steps of t1-row0 per iteration; GEMM2's
// ks-loop carries t1-row1. Only tile1's conv is exposed.
__global__ __launch_bounds__(512, 2)
void fused_all(const int* __restrict__ node_ids,
               const int* __restrict__ neighbors,
               const float* __restrict__ feat,
               const bf16* __restrict__ w1t, const bf16* __restrict__ w2t,
               const float* __restrict__ b1, const float* __restrict__ b2,
               float* __restrict__ out)
{
  __shared__ bf16 smem[2 * kBM * kXR * XPAD];   // 148608 B -> 1 block/CU
  bf16* xsA = smem;
  bf16* xsB = smem + (size_t)kBM * kXR * XPAD;
  bf16* hs  = smem;                              // h lives in xsA region

  const int tid  = threadIdx.x;
  const int wave = tid >> 6;       // 0..7
  const int lane = tid & 63;
  const int r = lane & 15;
  const int q = lane >> 4;
  const int f4 = lane << 2;

  const int tile0 = blockIdx.x;
  const int tile1 = blockIdx.x + 256;
  const int bbase0 = tile0 * kBM;
  const int bbase1 = tile1 * kBM;

  // ======= phase A: gather tile0 (2 rows per wave) -> xsA =======
  {
    int   mynA[2];
    f32x4 nodeA[2];
#pragma unroll
    for (int bb = 0; bb < 2; ++bb) {
      const int b = bbase0 + wave * 2 + bb;
      mynA[bb]  = neighbors[(size_t)b * kNB + lane];
      nodeA[bb] = *reinterpret_cast<const f32x4*>(feat + (size_t)node_ids[b] * kF + f4);
    }
#pragma unroll
    for (int bb = 0; bb < 2; ++bb)
      gather_row(feat, mynA[bb], f4, nodeA[bb],
                 xsA + (size_t)(wave * 2 + bb) * kXR * XPAD + f4);
  }
  __syncthreads();   // BAR1: xsA ready

  // ======= t1 gather prologue (ids + node rows for this wave's 2 rows) =======
  int   mynB0, mynB1;
  f32x4 nodeB0, nodeB1;
  {
    const int b0 = bbase1 + wave * 2 + 0;
    const int b1r = bbase1 + wave * 2 + 1;
    mynB0  = neighbors[(size_t)b0 * kNB + lane];
    mynB1  = neighbors[(size_t)b1r * kNB + lane];
    nodeB0 = *reinterpret_cast<const f32x4*>(feat + (size_t)node_ids[b0] * kF + f4);
    nodeB1 = *reinterpret_cast<const f32x4*>(feat + (size_t)node_ids[b1r] * kF + f4);
  }

  const int ntb = wave * 32;   // GEMM1 hc strip
  const int ob  = wave * 16;   // GEMM2 o strip

  // ======= phase B: GEMM1(t0) from xsA, woven with gather(t1 row0) =======
  f32x4 acc[kTO][2];
#pragma unroll
  for (int n = 0; n < 2; ++n) {
    const float bv = b1[ntb + n * 16 + r];
#pragma unroll
    for (int m = 0; m < kTO; ++m) acc[m][n] = (f32x4){bv, bv, bv, bv};
  }

  {
    float tkB[4][kK];
#pragma unroll
    for (int c = 0; c < 4; ++c)
#pragma unroll
      for (int k = 0; k < kK; ++k) tkB[c][k] = -INFINITY;
    f32x4 bufB[8];
#pragma unroll
    for (int i = 0; i < 8; ++i) bufB[i] = rowload(feat, mynB0, i, f4);

    for (int kk = 0; kk < 8; ++kk) {
      // --- 8 weave steps of t1-row0 ---
#pragma unroll
      for (int i = 0; i < 8; ++i) {
        const f32x4 v = bufB[i];
        if (kk < 7) bufB[i] = rowload(feat, mynB0, kk * 8 + i + 8, f4);
        ins4(v, tkB);
      }
      // --- GEMM1 kk body ---
      short8 a[kXR];
#pragma unroll
      for (int rr = 0; rr < kXR; ++rr)
        a[rr] = *reinterpret_cast<const short8*>(&xsA[(r * kXR + rr) * XPAD + kk * 32 + q * 8]);
#pragma unroll
      for (int dt = 0; dt < kKS; ++dt) {
        short8 bfr[2];
#pragma unroll
        for (int n = 0; n < 2; ++n)
          bfr[n] = *reinterpret_cast<const short8*>(
              &w1t[((size_t)(dt * kH + ntb + n * 16 + r)) * kF + kk * 32 + q * 8]);
#pragma unroll
        for (int m = 0; m < kTO; ++m)
#pragma unroll
          for (int n = 0; n < 2; ++n)
            acc[m][n] = __builtin_amdgcn_mfma_f32_16x16x32_bf16(a[m + dt], bfr[n], acc[m][n], 0, 0, 0);
      }
    }
    store_x(xsB + (size_t)(wave * 2 + 0) * kXR * XPAD + f4, nodeB0, tkB);
  }
  __syncthreads();   // BAR2: xsA reads done

  // ======= phase C: write h(t0) into xsA region =======
#pragma unroll
  for (int m = 0; m < kTO; ++m)
#pragma unroll
    for (int n = 0; n < 2; ++n)
#pragma unroll
      for (int j = 0; j < 4; ++j)
        hs[(q * 4 + j) * HPAD + m * kH + ntb + n * 16 + r] = __float2bfloat16(acc[m][n][j]);
  __syncthreads();   // BAR3: h(t0) ready

  // ======= phase D: GEMM2(t0) from hs, woven with gather(t1 row1) =======
  {
    float tkB[4][kK];
#pragma unroll
    for (int c = 0; c < 4; ++c)
#pragma unroll
      for (int k = 0; k < kK; ++k) tkB[c][k] = -INFINITY;
    f32x4 bufB[8];
#pragma unroll
    for (int i = 0; i < 8; ++i) bufB[i] = rowload(feat, mynB1, i, f4);

    f32x4 acc2;
    {
      const float bv = b2[ob + r];
      acc2 = (f32x4){bv, bv, bv, bv};
    }
    for (int c = 0; c < 8; ++c) {
      // --- 8 weave steps of t1-row1 ---
#pragma unroll
      for (int i = 0; i < 8; ++i) {
        const f32x4 v = bufB[i];
        if (c < 7) bufB[i] = rowload(feat, mynB1, c * 8 + i + 8, f4);
        ins4(v, tkB);
      }
      // --- 5 GEMM2 ks iters ---
#pragma unroll
      for (int j = 0; j < 5; ++j) {
        const int ks = c * 5 + j;
        short8 a2 = *reinterpret_cast<const short8*>(&hs[r * HPAD + ks * 32 + q * 8]);
        short8 b2f = *reinterpret_cast<const short8*>(
            &w2t[(size_t)(ob + r) * (kKS * kH) + ks * 32 + q * 8]);
        acc2 = __builtin_amdgcn_mfma_f32_16x16x32_bf16(a2, b2f, acc2, 0, 0, 0);
      }
    }
#pragma unroll
    for (int j = 0; j < 4; ++j)
      out[(size_t)(bbase0 + q * 4 + j) * kOUT + ob + r] = acc2[j];
    store_x(xsB + (size_t)(wave * 2 + 1) * kXR * XPAD + f4, nodeB1, tkB);
  }
  __syncthreads();   // BAR4: xsB complete, h(t0) consumers done

  // ======= phase E: GEMM1(t1) from xsB (plain) =======
#pragma unroll
  for (int n = 0; n < 2; ++n) {
    const float bv = b1[ntb + n * 16 + r];
#pragma unroll
    for (int m = 0; m < kTO; ++m) acc[m][n] = (f32x4){bv, bv, bv, bv};
  }
  for (int kk = 0; kk < 8; ++kk) {
    short8 a[kXR];
#pragma unroll
    for (int rr = 0; rr < kXR; ++rr)
      a[rr] = *reinterpret_cast<const short8*>(&xsB[(r * kXR + rr) * XPAD + kk * 32 + q * 8]);
#pragma unroll
    for (int dt = 0; dt < kKS; ++dt) {
      short8 bfr[2];
#pragma unroll
      for (int n = 0; n < 2; ++n)
        bfr[n] = *reinterpret_cast<const short8*>(
            &w1t[((size_t)(dt * kH + ntb + n * 16 + r)) * kF + kk * 32 + q * 8]);
#pragma unroll
      for (int m = 0; m < kTO; ++m)
#pragma unroll
        for (int n = 0; n < 2; ++n)
          acc[m][n] = __builtin_amdgcn_mfma_f32_16x16x32_bf16(a[m + dt], bfr[n], acc[m][n], 0, 0, 0);
    }
  }
  __syncthreads();   // BAR5: xsB reads done (xsA region free since BAR4)

  // ======= phase F: write h(t1) into xsA region =======
#pragma unroll
  for (int m = 0; m < kTO; ++m)
#pragma unroll
    for (int n = 0; n < 2; ++n)
#pragma unroll
      for (int j = 0; j < 4; ++j)
        hs[(q * 4 + j) * HPAD + m * kH + ntb + n * 16 + r] = __float2bfloat16(acc[m][n][j]);
  __syncthreads();   // BAR6: h(t1) ready

  // ======= phase G: GEMM2(t1) (plain) =======
  {
    f32x4 acc2;
    const float bv = b2[ob + r];
    acc2 = (f32x4){bv, bv, bv, bv};
    for (int ks = 0; ks < 40; ++ks) {
      short8 a2 = *reinterpret_cast<const short8*>(&hs[r * HPAD + ks * 32 + q * 8]);
      short8 b2f = *reinterpret_cast<const short8*>(
          &w2t[(size_t)(ob + r) * (kKS * kH) + ks * 32 + q * 8]);
      acc2 = __builtin_amdgcn_mfma_f32_16x16x32_bf16(a2, b2f, acc2, 0, 0, 0);
    }
#pragma unroll
    for (int j = 0; j < 4; ++j)
      out[(size_t)(bbase1 + q * 4 + j) * kOUT + ob + r] = acc2[j];
  }
}

extern "C" void kernel_launch(void* const* d_in, const int* in_sizes, int n_in,
                              void* d_out, int out_size, void* d_ws, size_t ws_size,
                              hipStream_t stream) {
  const int*   node_ids  = (const int*)  d_in[0];
  const int*   neighbors = (const int*)  d_in[1];
  const float* feat      = (const float*)d_in[2];
  const float* W1        = (const float*)d_in[3];
  const float* b1        = (const float*)d_in[4];
  const float* W2        = (const float*)d_in[5];
  const float* b2        = (const float*)d_in[6];
  float* out = (float*)d_out;

  char* ws = (char*)d_ws;
  bf16* w1t = (bf16*)(ws + W1T_OFF);
  bf16* w2t = (bf16*)(ws + W2T_OFF);

  convert_weights<<<1024, 256, 0, stream>>>(W1, W2, w1t, w2t);
  fused_all<<<kB / (kBM * kTiles), 512, 0, stream>>>(node_ids, neighbors, feat,
                                                     w1t, w2t, b1, b2, out);
}